// Round 10
// baseline (123.350 us; speedup 1.0000x reference)
//
#include <hip/hip_runtime.h>

#define NPTS 2048
#define KNBR 16

typedef __attribute__((ext_vector_type(8))) short bf16x8;
typedef __attribute__((ext_vector_type(4))) float f32x4;
union U8 { bf16x8 v; unsigned u[4]; };
union F4 { f32x4 v; float4 q; };

// gfx950 packed f32->bf16 (RNE)
static __device__ __forceinline__ unsigned pk2(float lo, float hi) {
    unsigned r;
    asm("v_cvt_pk_bf16_f32 %0, %1, %2" : "=v"(r) : "v"(lo), "v"(hi));
    return r;
}

// tanh-approx gelu (sigmoid form) — R5/R8/R9-proven __expf variant
static __device__ __forceinline__ float gelu(float x) {
    float x2 = x * x;
    float u  = x * fmaf(x2, 0.044715f, 1.0f);
    float e  = __expf(u * -1.5957691216057308f);
    return x * __builtin_amdgcn_rcpf(1.0f + e);
}

// LDS layout (shorts):
//   [0,20480)      w1f : W1 rows 128..287 (5 ks, rows>=259 zero), f=nt*5+ks
//   [20480,36864)  w2f : W2 (4 ks), f=nt*4+ks
//   [36864,53248)  w1d : (W1 rows 0..127)-(W1 rows 128..255), phase-B only
//   [53248,69632)  base: 16 waves x 4 nodes x 128 fp32 (node-major, c1-contig)
// NO hidden-staging region: layer1->layer2 bridge is in-wave shuffles.
#define LDS_BYTES 139264

__global__ __launch_bounds__(1024, 4) void edgeconv_fused(
    const float* __restrict__ h, const float* __restrict__ pos,
    const int* __restrict__ idx,
    const float* __restrict__ W1, const float* __restrict__ W2,
    const float* __restrict__ b1, const float* __restrict__ b2,
    const float* __restrict__ gamma, const float* __restrict__ beta,
    float* __restrict__ out)
{
    extern __shared__ short lds[];
    float* ldsF = (float*)lds;
    const int tid = threadIdx.x, wave = tid >> 6, lane = tid & 63;
    const int quad = lane >> 4, lm = lane & 15;

    // ---- phase A: swizzle weights (identical content to R9) ----
    for (int c = tid; c < 6656; c += 1024) {
        const int l = c & 63, fi = c >> 6;
        const int lrow = (l >> 4) * 8, lcol = l & 15;
        U8 t;
        if (fi < 40) {                        // w1f = W1b (rows 128..287)
            int ks = fi % 5, nt = fi / 5;
            int row0 = 128 + ks * 32 + lrow, col = nt * 16 + lcol;
            #pragma unroll
            for (int p = 0; p < 4; ++p) {
                int r0 = row0 + 2 * p;
                float v0 = (r0     < 259) ? W1[r0 * 128 + col]       : 0.f;
                float v1 = (r0 + 1 < 259) ? W1[(r0 + 1) * 128 + col] : 0.f;
                t.u[p] = pk2(v0, v1);
            }
        } else if (fi < 72) {                 // w2f
            int f2 = fi - 40, ks = f2 & 3, nt = f2 >> 2;
            int row0 = ks * 32 + lrow, col = nt * 16 + lcol;
            #pragma unroll
            for (int p = 0; p < 4; ++p)
                t.u[p] = pk2(W2[(row0 + 2*p) * 128 + col],
                             W2[(row0 + 2*p + 1) * 128 + col]);
        } else {                              // w1d = W1a - W1b (rows 0..127)
            int f2 = fi - 72, ks = f2 & 3, nt = f2 >> 2;
            int row0 = ks * 32 + lrow, col = nt * 16 + lcol;
            #pragma unroll
            for (int p = 0; p < 4; ++p) {
                int r0 = row0 + 2 * p;
                float v0 = W1[r0 * 128 + col]       - W1[(r0 + 128) * 128 + col];
                float v1 = W1[(r0 + 1) * 128 + col] - W1[(r0 + 129) * 128 + col];
                t.u[p] = pk2(v0, v1);
            }
        }
        ((bf16x8*)lds)[c] = t.v;
    }

    float b2v[8];
    #pragma unroll
    for (int nt = 0; nt < 8; ++nt) b2v[nt] = b2[nt * 16 + lm];
    const float gv0 = gamma[(quad * 2) * 16 + lm];
    const float gv1 = gamma[(quad * 2 + 1) * 16 + lm];
    const float be0 = beta[(quad * 2) * 16 + lm];
    const float be1 = beta[(quad * 2 + 1) * 16 + lm];

    __syncthreads();

    const bf16x8* w1frag  = (const bf16x8*)lds;          // W1b, f = nt*5+ks
    const bf16x8* w2frag  = (const bf16x8*)lds + 2560;   // f = nt*4+ks
    const bf16x8* w1dfrag = (const bf16x8*)lds + 4608;   // W1d, f = nt*4+ks
    float* baseF = ldsF + 26624 + wave * 512;            // [4 nodes][128 c1]

    const int sb = (blockIdx.x & 7) * 32 + (blockIdx.x >> 3);
    const int node0 = sb * 64 + wave * 4;
    const int bidx = node0 >> 11;
    const float4* hb4 = (const float4*)h + (size_t)bidx * NPTS * 32;
    const float*  pb  = pos + (size_t)bidx * NPTS * 3;
    const int nloc = node0 & 2047;

    int idxv[4];
    #pragma unroll
    for (int ni = 0; ni < 4; ++ni)
        idxv[ni] = idx[(node0 + ni) * KNBR + lm];

    // shuffle-bridge lane constants
    const int p   = quad & 1;
    const int qhi = quad >> 1;
    const int srcA = (p * 2 + (1 ^ qhi)) * 16 + lm;
    const int srcB = (p * 2 + qhi) * 16 + lm;

    // ---- phase B (transposed): base[c1][node] = h_i . W1d + b1 ----
    // D = A(w1d: c1 x k) * B(h_i frags: k x nodecol). Lane (q,lm) reg r holds
    // base[c1=16nt+4q+r][node0+(lm&3)]. Write node-major from lanes lm<4.
    {
        const float4* hsrc = hb4 + (size_t)(nloc + (lm & 3)) * 32;
        bf16x8 af[4];
        #pragma unroll
        for (int ks = 0; ks < 4; ++ks) {
            float4 p0 = hsrc[ks * 8 + quad * 2];
            float4 p1 = hsrc[ks * 8 + quad * 2 + 1];
            U8 t;
            t.u[0] = pk2(p0.x, p0.y); t.u[1] = pk2(p0.z, p0.w);
            t.u[2] = pk2(p1.x, p1.y); t.u[3] = pk2(p1.z, p1.w);
            af[ks] = t.v;
        }
        f32x4 bacc[8];
        #pragma unroll
        for (int nt = 0; nt < 8; ++nt) {
            F4 bi; bi.q = *(const float4*)(b1 + nt * 16 + quad * 4);
            bacc[nt] = bi.v;
        }
        #pragma unroll
        for (int ks = 0; ks < 4; ++ks)
            #pragma unroll
            for (int nt = 0; nt < 8; ++nt)
                bacc[nt] = __builtin_amdgcn_mfma_f32_16x16x32_bf16(
                    w1dfrag[(nt * 4 + ks) * 64 + lane], af[ks], bacc[nt], 0, 0, 0);

        if (lm < 4)
            #pragma unroll
            for (int nt = 0; nt < 8; ++nt) {
                F4 o; o.v = bacc[nt];
                *(float4*)(baseF + lm * 128 + nt * 16 + quad * 4) = o.q;
            }
    }
    __syncthreads();

    // ---- pair loop ----
    #pragma unroll
    for (int pr = 0; pr < 2; ++pr) {
        const int na = pr * 2, nb = pr * 2 + 1;
        const int ja = idxv[na], jb = idxv[nb];

        // msg fragments = bf16(h_j); placement valid as MFMA B-operand
        bf16x8 afA[4], afB[4];
        U8 rlA, rlB;
        {
            const float4* hjA4 = hb4 + (size_t)ja * 32;
            const float4* hjB4 = hb4 + (size_t)jb * 32;
            #pragma unroll
            for (int ks = 0; ks < 4; ++ks) {
                float4 j0 = hjA4[ks * 8 + quad * 2];
                float4 j1 = hjA4[ks * 8 + quad * 2 + 1];
                U8 t;
                t.u[0] = pk2(j0.x, j0.y); t.u[1] = pk2(j0.z, j0.w);
                t.u[2] = pk2(j1.x, j1.y); t.u[3] = pk2(j1.z, j1.w);
                afA[ks] = t.v;
                float4 k0 = hjB4[ks * 8 + quad * 2];
                float4 k1 = hjB4[ks * 8 + quad * 2 + 1];
                t.u[0] = pk2(k0.x, k0.y); t.u[1] = pk2(k0.z, k0.w);
                t.u[2] = pk2(k1.x, k1.y); t.u[3] = pk2(k1.z, k1.w);
                afB[ks] = t.v;
            }
            rlA.u[0] = 0; rlA.u[1] = 0; rlA.u[2] = 0; rlA.u[3] = 0;
            rlB.u[0] = 0; rlB.u[1] = 0; rlB.u[2] = 0; rlB.u[3] = 0;
            if (quad == 0) {
                int ia = nloc + na, ib = nloc + nb;
                rlA.u[0] = pk2(pb[3*ja]   - pb[3*ia],   pb[3*ja+1] - pb[3*ia+1]);
                rlA.u[1] = pk2(pb[3*ja+2] - pb[3*ia+2], 0.f);
                rlB.u[0] = pk2(pb[3*jb]   - pb[3*ib],   pb[3*jb+1] - pb[3*ib+1]);
                rlB.u[1] = pk2(pb[3*jb+2] - pb[3*ib+2], 0.f);
            }
        }

        // layer 1 (transposed): Ht[c1=16nt+4q+r][m=lm]; gelu; pack; shuffle
        // bridge straight into layer-2 A-fragments — no LDS staging, no waits.
        bf16x8 a2A[4], a2B[4];
        #pragma unroll
        for (int k2 = 0; k2 < 4; ++k2) {
            unsigned PA[2][2], PB[2][2];   // [lnt][h]: chans 16nt+4q+2h,+1
            #pragma unroll
            for (int lnt = 0; lnt < 2; ++lnt) {
                const int nt = k2 * 2 + lnt;
                F4 iA, iB;
                iA.q = *(const float4*)(baseF + na * 128 + nt * 16 + quad * 4);
                iB.q = *(const float4*)(baseF + nb * 128 + nt * 16 + quad * 4);
                f32x4 xA = iA.v, xB = iB.v;
                #pragma unroll
                for (int ks = 0; ks < 4; ++ks) {
                    bf16x8 w = w1frag[(nt * 5 + ks) * 64 + lane];
                    xA = __builtin_amdgcn_mfma_f32_16x16x32_bf16(w, afA[ks], xA, 0, 0, 0);
                    xB = __builtin_amdgcn_mfma_f32_16x16x32_bf16(w, afB[ks], xB, 0, 0, 0);
                }
                {
                    bf16x8 w = w1frag[(nt * 5 + 4) * 64 + lane];
                    xA = __builtin_amdgcn_mfma_f32_16x16x32_bf16(w, rlA.v, xA, 0, 0, 0);
                    xB = __builtin_amdgcn_mfma_f32_16x16x32_bf16(w, rlB.v, xB, 0, 0, 0);
                }
                PA[lnt][0] = pk2(gelu(xA[0]), gelu(xA[1]));
                PA[lnt][1] = pk2(gelu(xA[2]), gelu(xA[3]));
                PB[lnt][0] = pk2(gelu(xB[0]), gelu(xB[1]));
                PB[lnt][1] = pk2(gelu(xB[2]), gelu(xB[3]));
            }
            // 4-call cross-quad exchange (payload selected by src quad parity)
            {
                unsigned rA_ = (unsigned)__shfl((int)(p ? PA[0][0] : PA[1][0]), srcA, 64);
                unsigned rB_ = (unsigned)__shfl((int)(p ? PA[1][0] : PA[0][0]), srcB, 64);
                unsigned rC_ = (unsigned)__shfl((int)(p ? PA[0][1] : PA[1][1]), srcA, 64);
                unsigned rD_ = (unsigned)__shfl((int)(p ? PA[1][1] : PA[0][1]), srcB, 64);
                U8 ua;
                ua.u[0] = qhi ? rA_ : rB_;
                ua.u[1] = qhi ? rC_ : rD_;
                ua.u[2] = qhi ? rB_ : rA_;
                ua.u[3] = qhi ? rD_ : rC_;
                a2A[k2] = ua.v;
            }
            {
                unsigned rA_ = (unsigned)__shfl((int)(p ? PB[0][0] : PB[1][0]), srcA, 64);
                unsigned rB_ = (unsigned)__shfl((int)(p ? PB[1][0] : PB[0][0]), srcB, 64);
                unsigned rC_ = (unsigned)__shfl((int)(p ? PB[0][1] : PB[1][1]), srcA, 64);
                unsigned rD_ = (unsigned)__shfl((int)(p ? PB[1][1] : PB[0][1]), srcB, 64);
                U8 ub;
                ub.u[0] = qhi ? rA_ : rB_;
                ub.u[1] = qhi ? rC_ : rD_;
                ub.u[2] = qhi ? rB_ : rA_;
                ub.u[3] = qhi ? rD_ : rC_;
                a2B[k2] = ub.v;
            }
        }

        // layer 2 (original orientation, unchanged) + max/min epilogue
        float vA[8], vB[8];
        #pragma unroll
        for (int nt = 0; nt < 8; ++nt) {
            f32x4 cA = (f32x4){0.f, 0.f, 0.f, 0.f};
            f32x4 cB = (f32x4){0.f, 0.f, 0.f, 0.f};
            #pragma unroll
            for (int ks = 0; ks < 4; ++ks) {
                bf16x8 w = w2frag[(nt * 4 + ks) * 64 + lane];
                cA = __builtin_amdgcn_mfma_f32_16x16x32_bf16(a2A[ks], w, cA, 0, 0, 0);
                cB = __builtin_amdgcn_mfma_f32_16x16x32_bf16(a2B[ks], w, cB, 0, 0, 0);
            }
            float mxA = fmaxf(fmaxf(cA[0], cA[1]), fmaxf(cA[2], cA[3]));
            float mnA = fminf(fminf(cA[0], cA[1]), fminf(cA[2], cA[3]));
            float mxB = fmaxf(fmaxf(cB[0], cB[1]), fmaxf(cB[2], cB[3]));
            float mnB = fminf(fminf(cB[0], cB[1]), fminf(cB[2], cB[3]));
            mxA = fmaxf(mxA, __shfl_xor(mxA, 16, 64));
            mxA = fmaxf(mxA, __shfl_xor(mxA, 32, 64));
            mnA = fminf(mnA, __shfl_xor(mnA, 16, 64));
            mnA = fminf(mnA, __shfl_xor(mnA, 32, 64));
            mxB = fmaxf(mxB, __shfl_xor(mxB, 16, 64));
            mxB = fmaxf(mxB, __shfl_xor(mxB, 32, 64));
            mnB = fminf(mnB, __shfl_xor(mnB, 16, 64));
            mnB = fminf(mnB, __shfl_xor(mnB, 32, 64));
            vA[nt] = fmaxf(gelu(mxA + b2v[nt]), gelu(mnA + b2v[nt]));
            vB[nt] = fmaxf(gelu(mxB + b2v[nt]), gelu(mnB + b2v[nt]));
        }

        // layernorm + store
        #pragma unroll
        for (int u = 0; u < 2; ++u) {
            const float* v = u ? vB : vA;
            float s = 0.f, s2 = 0.f;
            #pragma unroll
            for (int nt = 0; nt < 8; ++nt) { s += v[nt]; s2 += v[nt] * v[nt]; }
            #pragma unroll
            for (int off = 1; off <= 8; off <<= 1) {
                s  += __shfl_xor(s,  off, 64);
                s2 += __shfl_xor(s2, off, 64);
            }
            const float mu  = s * (1.0f / 128.0f);
            const float var = s2 * (1.0f / 128.0f) - mu * mu;
            const float inv = rsqrtf(var + 1e-5f);
            float* orow = out + (size_t)(node0 + pr * 2 + u) * 128;
            orow[(quad * 2) * 16 + lm]     = (v[quad * 2]     - mu) * inv * gv0 + be0;
            orow[(quad * 2 + 1) * 16 + lm] = (v[quad * 2 + 1] - mu) * inv * gv1 + be1;
        }
    }
}

extern "C" void kernel_launch(void* const* d_in, const int* in_sizes, int n_in,
                              void* d_out, int out_size, void* d_ws, size_t ws_size,
                              hipStream_t stream) {
    const float* h     = (const float*)d_in[0];
    const float* pos   = (const float*)d_in[1];
    const int*   idx   = (const int*)  d_in[2];
    const float* W1    = (const float*)d_in[3];
    const float* b1    = (const float*)d_in[4];
    const float* W2    = (const float*)d_in[5];
    const float* b2    = (const float*)d_in[6];
    const float* gamma = (const float*)d_in[7];
    const float* beta  = (const float*)d_in[8];
    float* out = (float*)d_out;

    hipFuncSetAttribute((const void*)edgeconv_fused,
                        hipFuncAttributeMaxDynamicSharedMemorySize, LDS_BYTES);
    edgeconv_fused<<<256, 1024, LDS_BYTES, stream>>>(
        h, pos, idx, W1, W2, b1, b2, gamma, beta, out);
}

// Round 11
// 120.077 us; speedup vs baseline: 1.0273x; 1.0273x over previous
//
#include <hip/hip_runtime.h>

#define NPTS 2048
#define KNBR 16

typedef __attribute__((ext_vector_type(8))) short bf16x8;
typedef __attribute__((ext_vector_type(4))) float f32x4;
union U8 { bf16x8 v; unsigned u[4]; };

// gfx950 packed f32->bf16 (RNE)
static __device__ __forceinline__ unsigned pk2(float lo, float hi) {
    unsigned r;
    asm("v_cvt_pk_bf16_f32 %0, %1, %2" : "=v"(r) : "v"(lo), "v"(hi));
    return r;
}

// tanh-approx gelu, sigmoid form via exp2.
// exp(u*-1.5957691216) == exp2(u*-2.3022083). Exonerated: R6/R7 failures were
// STG misalignment / LDS overflow, not this.
static __device__ __forceinline__ float gelu(float x) {
    float x2 = x * x;
    float u  = x * fmaf(x2, 0.044715f, 1.0f);
    float e  = __builtin_amdgcn_exp2f(u * -2.3022083f);
    return x * __builtin_amdgcn_rcpf(1.0f + e);
}

// LDS layout (shorts):
//   [0,20480)      w1f : W1 rows 128..287 (5 ks, rows>=259 zero), f=nt*5+ks
//   [20480,36864)  w2f : W2 (4 ks), f=nt*4+ks
//   [36864,53248)  w1d : (W1 rows 0..127)-(W1 rows 128..255), phase-B only
//   [36864,57344)  staging (overlays w1d after barrier):
//                  16 waves x [2 nodes][16 m][STG=40]  (wave15 ends at 57344)
// total = 57344 shorts = 114688 B.  STG must be mult of 8 (16B-aligned b128).
#define STG 40
#define LDS_BYTES 114688

__global__ __launch_bounds__(1024, 4) void edgeconv_fused(
    const float* __restrict__ h, const float* __restrict__ pos,
    const int* __restrict__ idx,
    const float* __restrict__ W1, const float* __restrict__ W2,
    const float* __restrict__ b1, const float* __restrict__ b2,
    const float* __restrict__ gamma, const float* __restrict__ beta,
    float* __restrict__ out)
{
    extern __shared__ short lds[];
    const int tid = threadIdx.x, wave = tid >> 6, lane = tid & 63;
    const int quad = lane >> 4, lm = lane & 15;

    // ---- phase A: swizzle weights (identical content to R9) ----
    for (int c = tid; c < 6656; c += 1024) {
        const int l = c & 63, fi = c >> 6;
        const int lrow = (l >> 4) * 8, lcol = l & 15;
        U8 t;
        if (fi < 40) {                        // w1f = W1b (rows 128..287)
            int ks = fi % 5, nt = fi / 5;
            int row0 = 128 + ks * 32 + lrow, col = nt * 16 + lcol;
            #pragma unroll
            for (int p = 0; p < 4; ++p) {
                int r0 = row0 + 2 * p;
                float v0 = (r0     < 259) ? W1[r0 * 128 + col]       : 0.f;
                float v1 = (r0 + 1 < 259) ? W1[(r0 + 1) * 128 + col] : 0.f;
                t.u[p] = pk2(v0, v1);
            }
        } else if (fi < 72) {                 // w2f
            int f2 = fi - 40, ks = f2 & 3, nt = f2 >> 2;
            int row0 = ks * 32 + lrow, col = nt * 16 + lcol;
            #pragma unroll
            for (int p = 0; p < 4; ++p)
                t.u[p] = pk2(W2[(row0 + 2*p) * 128 + col],
                             W2[(row0 + 2*p + 1) * 128 + col]);
        } else {                              // w1d = W1a - W1b (rows 0..127)
            int f2 = fi - 72, ks = f2 & 3, nt = f2 >> 2;
            int row0 = ks * 32 + lrow, col = nt * 16 + lcol;
            #pragma unroll
            for (int p = 0; p < 4; ++p) {
                int r0 = row0 + 2 * p;
                float v0 = W1[r0 * 128 + col]       - W1[(r0 + 128) * 128 + col];
                float v1 = W1[(r0 + 1) * 128 + col] - W1[(r0 + 129) * 128 + col];
                t.u[p] = pk2(v0, v1);
            }
        }
        ((bf16x8*)lds)[c] = t.v;
    }

    float b1v[8], b2v[8];
    #pragma unroll
    for (int nt = 0; nt < 8; ++nt) {
        b1v[nt] = b1[nt * 16 + lm];
        b2v[nt] = b2[nt * 16 + lm];
    }
    const float gv0 = gamma[(quad * 2) * 16 + lm];
    const float gv1 = gamma[(quad * 2 + 1) * 16 + lm];
    const float be0 = beta[(quad * 2) * 16 + lm];
    const float be1 = beta[(quad * 2 + 1) * 16 + lm];

    __syncthreads();

    const bf16x8* w1frag  = (const bf16x8*)lds;          // W1b, f = nt*5+ks
    const bf16x8* w2frag  = (const bf16x8*)lds + 2560;   // f = nt*4+ks
    const bf16x8* w1dfrag = (const bf16x8*)lds + 4608;   // W1d, f = nt*4+ks
    short* stg = lds + 36864 + wave * 1280;              // [2][16][STG]

    const int sb = (blockIdx.x & 7) * 32 + (blockIdx.x >> 3);
    const int node0 = sb * 64 + wave * 4;
    const int bidx = node0 >> 11;
    const float4* hb4 = (const float4*)h + (size_t)bidx * NPTS * 32;
    const float*  pb  = pos + (size_t)bidx * NPTS * 3;
    const int nloc = node0 & 2047;

    int idxv[4];
    #pragma unroll
    for (int ni = 0; ni < 4; ++ni)
        idxv[ni] = idx[(node0 + ni) * KNBR + lm];

    // ---- phase B: basev[nt][r] = base(node0+r, nt*16+lm), kept in VGPRs ----
    // A row m holds h_{node0+(m&3)}; C row quad*4+r -> node r for every quad,
    // so all 64 lanes hold all 4 nodes' base at their own column. (Exonerated:
    // R6/R7 failures were sizing bugs, not this mapping.)
    f32x4 basev[8];
    {
        const float4* hsrc = hb4 + (size_t)(nloc + (lm & 3)) * 32;
        bf16x8 af[4];
        #pragma unroll
        for (int ks = 0; ks < 4; ++ks) {
            float4 p0 = hsrc[ks * 8 + quad * 2];
            float4 p1 = hsrc[ks * 8 + quad * 2 + 1];
            U8 t;
            t.u[0] = pk2(p0.x, p0.y); t.u[1] = pk2(p0.z, p0.w);
            t.u[2] = pk2(p1.x, p1.y); t.u[3] = pk2(p1.z, p1.w);
            af[ks] = t.v;
        }
        #pragma unroll
        for (int nt = 0; nt < 8; ++nt)
            basev[nt] = (f32x4){b1v[nt], b1v[nt], b1v[nt], b1v[nt]};
        #pragma unroll
        for (int ks = 0; ks < 4; ++ks)
            #pragma unroll
            for (int nt = 0; nt < 8; ++nt)
                basev[nt] = __builtin_amdgcn_mfma_f32_16x16x32_bf16(
                    af[ks], w1dfrag[(nt * 4 + ks) * 64 + lane], basev[nt], 0, 0, 0);
    }
    __syncthreads();    // staging overlays w1d beyond this point

    // ---- pair loop ----
    #pragma unroll
    for (int pr = 0; pr < 2; ++pr) {
        const int na = pr * 2, nb = pr * 2 + 1;
        const int ja = idxv[na], jb = idxv[nb];

        // A-fragments = bf16(h_j) directly (W1d trick)
        bf16x8 afA[4], afB[4];
        U8 rlA, rlB;
        {
            const float4* hjA4 = hb4 + (size_t)ja * 32;
            const float4* hjB4 = hb4 + (size_t)jb * 32;
            #pragma unroll
            for (int ks = 0; ks < 4; ++ks) {
                float4 j0 = hjA4[ks * 8 + quad * 2];
                float4 j1 = hjA4[ks * 8 + quad * 2 + 1];
                U8 t;
                t.u[0] = pk2(j0.x, j0.y); t.u[1] = pk2(j0.z, j0.w);
                t.u[2] = pk2(j1.x, j1.y); t.u[3] = pk2(j1.z, j1.w);
                afA[ks] = t.v;
                float4 k0 = hjB4[ks * 8 + quad * 2];
                float4 k1 = hjB4[ks * 8 + quad * 2 + 1];
                t.u[0] = pk2(k0.x, k0.y); t.u[1] = pk2(k0.z, k0.w);
                t.u[2] = pk2(k1.x, k1.y); t.u[3] = pk2(k1.z, k1.w);
                afB[ks] = t.v;
            }
            rlA.u[0] = 0; rlA.u[1] = 0; rlA.u[2] = 0; rlA.u[3] = 0;
            rlB.u[0] = 0; rlB.u[1] = 0; rlB.u[2] = 0; rlB.u[3] = 0;
            if (quad == 0) {
                int ia = nloc + na, ib = nloc + nb;
                rlA.u[0] = pk2(pb[3*ja]   - pb[3*ia],   pb[3*ja+1] - pb[3*ia+1]);
                rlA.u[1] = pk2(pb[3*ja+2] - pb[3*ia+2], 0.f);
                rlB.u[0] = pk2(pb[3*jb]   - pb[3*ib],   pb[3*jb+1] - pb[3*ib+1]);
                rlB.u[1] = pk2(pb[3*jb+2] - pb[3*ib+2], 0.f);
            }
        }

        // layer 1, 32-col chunks; immediate LDS re-read as layer-2 A-frags
        bf16x8 a2A[4], a2B[4];
        #pragma unroll
        for (int ks2 = 0; ks2 < 4; ++ks2) {
            #pragma unroll
            for (int ntl = 0; ntl < 2; ++ntl) {
                const int nt = ks2 * 2 + ntl;
                float bA = basev[nt][na];
                float bB = basev[nt][nb];
                f32x4 cA = (f32x4){bA, bA, bA, bA};
                f32x4 cB = (f32x4){bB, bB, bB, bB};
                #pragma unroll
                for (int ks = 0; ks < 4; ++ks) {
                    bf16x8 w = w1frag[(nt * 5 + ks) * 64 + lane];
                    cA = __builtin_amdgcn_mfma_f32_16x16x32_bf16(afA[ks], w, cA, 0, 0, 0);
                    cB = __builtin_amdgcn_mfma_f32_16x16x32_bf16(afB[ks], w, cB, 0, 0, 0);
                }
                {
                    bf16x8 w = w1frag[(nt * 5 + 4) * 64 + lane];
                    cA = __builtin_amdgcn_mfma_f32_16x16x32_bf16(rlA.v, w, cA, 0, 0, 0);
                    cB = __builtin_amdgcn_mfma_f32_16x16x32_bf16(rlB.v, w, cB, 0, 0, 0);
                }
                #pragma unroll
                for (int r = 0; r < 4; ++r) {
                    float gA = gelu(cA[r]), gB = gelu(cB[r]);
                    stg[      (quad * 4 + r) * STG + ntl * 16 + lm] = (short)pk2(gA, gA);
                    stg[640 + (quad * 4 + r) * STG + ntl * 16 + lm] = (short)pk2(gB, gB);
                }
            }
            asm volatile("s_waitcnt lgkmcnt(0)" ::: "memory");
            a2A[ks2] = *(const bf16x8*)(stg +       lm * STG + quad * 8);
            a2B[ks2] = *(const bf16x8*)(stg + 640 + lm * STG + quad * 8);
            asm volatile("s_waitcnt lgkmcnt(0)" ::: "memory");
        }

        // layer 2 + max/min epilogue
        float vA[8], vB[8];
        #pragma unroll
        for (int nt = 0; nt < 8; ++nt) {
            f32x4 cA = (f32x4){0.f, 0.f, 0.f, 0.f};
            f32x4 cB = (f32x4){0.f, 0.f, 0.f, 0.f};
            #pragma unroll
            for (int ks = 0; ks < 4; ++ks) {
                bf16x8 w = w2frag[(nt * 4 + ks) * 64 + lane];
                cA = __builtin_amdgcn_mfma_f32_16x16x32_bf16(a2A[ks], w, cA, 0, 0, 0);
                cB = __builtin_amdgcn_mfma_f32_16x16x32_bf16(a2B[ks], w, cB, 0, 0, 0);
            }
            float mxA = fmaxf(fmaxf(cA[0], cA[1]), fmaxf(cA[2], cA[3]));
            float mnA = fminf(fminf(cA[0], cA[1]), fminf(cA[2], cA[3]));
            float mxB = fmaxf(fmaxf(cB[0], cB[1]), fmaxf(cB[2], cB[3]));
            float mnB = fminf(fminf(cB[0], cB[1]), fminf(cB[2], cB[3]));
            mxA = fmaxf(mxA, __shfl_xor(mxA, 16, 64));
            mxA = fmaxf(mxA, __shfl_xor(mxA, 32, 64));
            mnA = fminf(mnA, __shfl_xor(mnA, 16, 64));
            mnA = fminf(mnA, __shfl_xor(mnA, 32, 64));
            mxB = fmaxf(mxB, __shfl_xor(mxB, 16, 64));
            mxB = fmaxf(mxB, __shfl_xor(mxB, 32, 64));
            mnB = fminf(mnB, __shfl_xor(mnB, 16, 64));
            mnB = fminf(mnB, __shfl_xor(mnB, 32, 64));
            vA[nt] = fmaxf(gelu(mxA + b2v[nt]), gelu(mnA + b2v[nt]));
            vB[nt] = fmaxf(gelu(mxB + b2v[nt]), gelu(mnB + b2v[nt]));
        }

        // layernorm + store
        #pragma unroll
        for (int u = 0; u < 2; ++u) {
            const float* v = u ? vB : vA;
            float s = 0.f, s2 = 0.f;
            #pragma unroll
            for (int nt = 0; nt < 8; ++nt) { s += v[nt]; s2 += v[nt] * v[nt]; }
            #pragma unroll
            for (int off = 1; off <= 8; off <<= 1) {
                s  += __shfl_xor(s,  off, 64);
                s2 += __shfl_xor(s2, off, 64);
            }
            const float mu  = s * (1.0f / 128.0f);
            const float var = s2 * (1.0f / 128.0f) - mu * mu;
            const float inv = rsqrtf(var + 1e-5f);
            float* orow = out + (size_t)(node0 + pr * 2 + u) * 128;
            orow[(quad * 2) * 16 + lm]     = (v[quad * 2]     - mu) * inv * gv0 + be0;
            orow[(quad * 2 + 1) * 16 + lm] = (v[quad * 2 + 1] - mu) * inv * gv1 + be1;
        }
    }
}

extern "C" void kernel_launch(void* const* d_in, const int* in_sizes, int n_in,
                              void* d_out, int out_size, void* d_ws, size_t ws_size,
                              hipStream_t stream) {
    const float* h     = (const float*)d_in[0];
    const float* pos   = (const float*)d_in[1];
    const int*   idx   = (const int*)  d_in[2];
    const float* W1    = (const float*)d_in[3];
    const float* b1    = (const float*)d_in[4];
    const float* W2    = (const float*)d_in[5];
    const float* b2    = (const float*)d_in[6];
    const float* gamma = (const float*)d_in[7];
    const float* beta  = (const float*)d_in[8];
    float* out = (float*)d_out;

    hipFuncSetAttribute((const void*)edgeconv_fused,
                        hipFuncAttributeMaxDynamicSharedMemorySize, LDS_BYTES);
    edgeconv_fused<<<256, 1024, LDS_BYTES, stream>>>(
        h, pos, idx, W1, W2, b1, b2, gamma, beta, out);
}

// Round 12
// 119.368 us; speedup vs baseline: 1.0334x; 1.0059x over previous
//
#include <hip/hip_runtime.h>

#define NPTS 2048
#define KNBR 16

typedef __attribute__((ext_vector_type(8))) short bf16x8;
typedef __attribute__((ext_vector_type(4))) float f32x4;
union U8 { bf16x8 v; unsigned u[4]; };
union F4 { f32x4 v; float4 q; };

// gfx950 packed f32->bf16 (RNE)
static __device__ __forceinline__ unsigned pk2(float lo, float hi) {
    unsigned r;
    asm("v_cvt_pk_bf16_f32 %0, %1, %2" : "=v"(r) : "v"(lo), "v"(hi));
    return r;
}

// tanh-approx gelu, sigmoid form via exp2 (R11-proven)
static __device__ __forceinline__ float gelu(float x) {
    float x2 = x * x;
    float u  = x * fmaf(x2, 0.044715f, 1.0f);
    float e  = __builtin_amdgcn_exp2f(u * -2.3022083f);
    return x * __builtin_amdgcn_rcpf(1.0f + e);
}

// LDS layout (shorts):
//   [0,20480)      w1f : W1 rows 128..287 (5 ks, rows>=259 zero), f=nt*5+ks
//   [20480,36864)  w2f : W2 (4 ks), f=nt*4+ks
//   [36864,53248)  w1d : (W1 rows 0..127)-(W1 rows 128..255), phase-B only
//   [36864,57344)  staging (overlays w1d): 16 waves x [2 nodes][16 m][STG=40]
//                  (transposed-L1 layout: m-major, c1-contiguous)
//   [57344,73728)  baseF: 16 waves x [4 nodes][128 c1] fp32
// total 73728 shorts = 147456 B.  STG=40: b64 writes 8B-aligned, b128 reads
// 16B-aligned (lm*80 = 16*5*lm), 2-way banks (free).
#define STG 40
#define LDS_BYTES 147456

__global__ __launch_bounds__(1024, 4) void edgeconv_fused(
    const float* __restrict__ h, const float* __restrict__ pos,
    const int* __restrict__ idx,
    const float* __restrict__ W1, const float* __restrict__ W2,
    const float* __restrict__ b1, const float* __restrict__ b2,
    const float* __restrict__ gamma, const float* __restrict__ beta,
    float* __restrict__ out)
{
    extern __shared__ short lds[];
    float* ldsF = (float*)lds;
    const int tid = threadIdx.x, wave = tid >> 6, lane = tid & 63;
    const int quad = lane >> 4, lm = lane & 15;

    // ---- phase A: swizzle weights (identical content to R9/R11) ----
    for (int c = tid; c < 6656; c += 1024) {
        const int l = c & 63, fi = c >> 6;
        const int lrow = (l >> 4) * 8, lcol = l & 15;
        U8 t;
        if (fi < 40) {                        // w1f = W1b (rows 128..287)
            int ks = fi % 5, nt = fi / 5;
            int row0 = 128 + ks * 32 + lrow, col = nt * 16 + lcol;
            #pragma unroll
            for (int p = 0; p < 4; ++p) {
                int r0 = row0 + 2 * p;
                float v0 = (r0     < 259) ? W1[r0 * 128 + col]       : 0.f;
                float v1 = (r0 + 1 < 259) ? W1[(r0 + 1) * 128 + col] : 0.f;
                t.u[p] = pk2(v0, v1);
            }
        } else if (fi < 72) {                 // w2f
            int f2 = fi - 40, ks = f2 & 3, nt = f2 >> 2;
            int row0 = ks * 32 + lrow, col = nt * 16 + lcol;
            #pragma unroll
            for (int p = 0; p < 4; ++p)
                t.u[p] = pk2(W2[(row0 + 2*p) * 128 + col],
                             W2[(row0 + 2*p + 1) * 128 + col]);
        } else {                              // w1d = W1a - W1b (rows 0..127)
            int f2 = fi - 72, ks = f2 & 3, nt = f2 >> 2;
            int row0 = ks * 32 + lrow, col = nt * 16 + lcol;
            #pragma unroll
            for (int p = 0; p < 4; ++p) {
                int r0 = row0 + 2 * p;
                float v0 = W1[r0 * 128 + col]       - W1[(r0 + 128) * 128 + col];
                float v1 = W1[(r0 + 1) * 128 + col] - W1[(r0 + 129) * 128 + col];
                t.u[p] = pk2(v0, v1);
            }
        }
        ((bf16x8*)lds)[c] = t.v;
    }

    float b2v[8];
    #pragma unroll
    for (int nt = 0; nt < 8; ++nt) b2v[nt] = b2[nt * 16 + lm];
    const float gv0 = gamma[(quad * 2) * 16 + lm];
    const float gv1 = gamma[(quad * 2 + 1) * 16 + lm];
    const float be0 = beta[(quad * 2) * 16 + lm];
    const float be1 = beta[(quad * 2 + 1) * 16 + lm];

    __syncthreads();

    const bf16x8* w1frag  = (const bf16x8*)lds;          // W1b, f = nt*5+ks
    const bf16x8* w2frag  = (const bf16x8*)lds + 2560;   // f = nt*4+ks
    const bf16x8* w1dfrag = (const bf16x8*)lds + 4608;   // W1d, f = nt*4+ks
    short* stg   = lds  + 36864 + wave * 1280;           // [2][16][STG]
    float* baseF = ldsF + 28672 + wave * 512;            // [4 nodes][128 c1]

    const int sb = (blockIdx.x & 7) * 32 + (blockIdx.x >> 3);
    const int node0 = sb * 64 + wave * 4;
    const int bidx = node0 >> 11;
    const float4* hb4 = (const float4*)h + (size_t)bidx * NPTS * 32;
    const float*  pb  = pos + (size_t)bidx * NPTS * 3;
    const int nloc = node0 & 2047;

    int idxv[4];
    #pragma unroll
    for (int ni = 0; ni < 4; ++ni)
        idxv[ni] = idx[(node0 + ni) * KNBR + lm];

    // ---- phase B (transposed, R10-proven): base[c1][node] = h_i.W1d + b1 ----
    {
        const float4* hsrc = hb4 + (size_t)(nloc + (lm & 3)) * 32;
        bf16x8 af[4];
        #pragma unroll
        for (int ks = 0; ks < 4; ++ks) {
            float4 p0 = hsrc[ks * 8 + quad * 2];
            float4 p1 = hsrc[ks * 8 + quad * 2 + 1];
            U8 t;
            t.u[0] = pk2(p0.x, p0.y); t.u[1] = pk2(p0.z, p0.w);
            t.u[2] = pk2(p1.x, p1.y); t.u[3] = pk2(p1.z, p1.w);
            af[ks] = t.v;
        }
        f32x4 bacc[8];
        #pragma unroll
        for (int nt = 0; nt < 8; ++nt) {
            F4 bi; bi.q = *(const float4*)(b1 + nt * 16 + quad * 4);
            bacc[nt] = bi.v;
        }
        #pragma unroll
        for (int ks = 0; ks < 4; ++ks)
            #pragma unroll
            for (int nt = 0; nt < 8; ++nt)
                bacc[nt] = __builtin_amdgcn_mfma_f32_16x16x32_bf16(
                    w1dfrag[(nt * 4 + ks) * 64 + lane], af[ks], bacc[nt], 0, 0, 0);

        if (lm < 4)
            #pragma unroll
            for (int nt = 0; nt < 8; ++nt) {
                F4 o; o.v = bacc[nt];
                *(float4*)(baseF + lm * 128 + nt * 16 + quad * 4) = o.q;
            }
    }
    __syncthreads();    // staging overlays w1d beyond this point

    // ---- pair loop ----
    #pragma unroll
    for (int pr = 0; pr < 2; ++pr) {
        const int na = pr * 2, nb = pr * 2 + 1;
        const int ja = idxv[na], jb = idxv[nb];

        // msg fragments = bf16(h_j); valid as MFMA B-operand (R10-proven)
        bf16x8 afA[4], afB[4];
        U8 rlA, rlB;
        {
            const float4* hjA4 = hb4 + (size_t)ja * 32;
            const float4* hjB4 = hb4 + (size_t)jb * 32;
            #pragma unroll
            for (int ks = 0; ks < 4; ++ks) {
                float4 j0 = hjA4[ks * 8 + quad * 2];
                float4 j1 = hjA4[ks * 8 + quad * 2 + 1];
                U8 t;
                t.u[0] = pk2(j0.x, j0.y); t.u[1] = pk2(j0.z, j0.w);
                t.u[2] = pk2(j1.x, j1.y); t.u[3] = pk2(j1.z, j1.w);
                afA[ks] = t.v;
                float4 k0 = hjB4[ks * 8 + quad * 2];
                float4 k1 = hjB4[ks * 8 + quad * 2 + 1];
                t.u[0] = pk2(k0.x, k0.y); t.u[1] = pk2(k0.z, k0.w);
                t.u[2] = pk2(k1.x, k1.y); t.u[3] = pk2(k1.z, k1.w);
                afB[ks] = t.v;
            }
            rlA.u[0] = 0; rlA.u[1] = 0; rlA.u[2] = 0; rlA.u[3] = 0;
            rlB.u[0] = 0; rlB.u[1] = 0; rlB.u[2] = 0; rlB.u[3] = 0;
            if (quad == 0) {
                int ia = nloc + na, ib = nloc + nb;
                rlA.u[0] = pk2(pb[3*ja]   - pb[3*ia],   pb[3*ja+1] - pb[3*ia+1]);
                rlA.u[1] = pk2(pb[3*ja+2] - pb[3*ia+2], 0.f);
                rlB.u[0] = pk2(pb[3*jb]   - pb[3*ib],   pb[3*jb+1] - pb[3*ib+1]);
                rlB.u[1] = pk2(pb[3*jb+2] - pb[3*ib+2], 0.f);
            }
        }

        // layer 1 (transposed): lane(q,lm) reg r = Ht[c1=16nt+4q+r][m=lm].
        // Staging [m][c1-contig]: per nt per node, 2 pk2 + ONE ds_write_b64;
        // L2 A-frag read = b128 at [lm][quad*8].
        bf16x8 a2A[4], a2B[4];
        #pragma unroll
        for (int ks2 = 0; ks2 < 4; ++ks2) {
            #pragma unroll
            for (int ntl = 0; ntl < 2; ++ntl) {
                const int nt = ks2 * 2 + ntl;
                F4 iA, iB;
                iA.q = *(const float4*)(baseF + na * 128 + nt * 16 + quad * 4);
                iB.q = *(const float4*)(baseF + nb * 128 + nt * 16 + quad * 4);
                f32x4 xA = iA.v, xB = iB.v;
                #pragma unroll
                for (int ks = 0; ks < 4; ++ks) {
                    bf16x8 w = w1frag[(nt * 5 + ks) * 64 + lane];
                    xA = __builtin_amdgcn_mfma_f32_16x16x32_bf16(w, afA[ks], xA, 0, 0, 0);
                    xB = __builtin_amdgcn_mfma_f32_16x16x32_bf16(w, afB[ks], xB, 0, 0, 0);
                }
                {
                    bf16x8 w = w1frag[(nt * 5 + 4) * 64 + lane];
                    xA = __builtin_amdgcn_mfma_f32_16x16x32_bf16(w, rlA.v, xA, 0, 0, 0);
                    xB = __builtin_amdgcn_mfma_f32_16x16x32_bf16(w, rlB.v, xB, 0, 0, 0);
                }
                uint2 wA, wB;
                wA.x = pk2(gelu(xA[0]), gelu(xA[1]));
                wA.y = pk2(gelu(xA[2]), gelu(xA[3]));
                wB.x = pk2(gelu(xB[0]), gelu(xB[1]));
                wB.y = pk2(gelu(xB[2]), gelu(xB[3]));
                *(uint2*)(stg +       lm * STG + ntl * 16 + quad * 4) = wA;
                *(uint2*)(stg + 640 + lm * STG + ntl * 16 + quad * 4) = wB;
            }
            asm volatile("s_waitcnt lgkmcnt(0)" ::: "memory");
            a2A[ks2] = *(const bf16x8*)(stg +       lm * STG + quad * 8);
            a2B[ks2] = *(const bf16x8*)(stg + 640 + lm * STG + quad * 8);
            asm volatile("s_waitcnt lgkmcnt(0)" ::: "memory");
        }

        // layer 2 (unchanged orientation) + max/min epilogue
        float vA[8], vB[8];
        #pragma unroll
        for (int nt = 0; nt < 8; ++nt) {
            f32x4 cA = (f32x4){0.f, 0.f, 0.f, 0.f};
            f32x4 cB = (f32x4){0.f, 0.f, 0.f, 0.f};
            #pragma unroll
            for (int ks = 0; ks < 4; ++ks) {
                bf16x8 w = w2frag[(nt * 4 + ks) * 64 + lane];
                cA = __builtin_amdgcn_mfma_f32_16x16x32_bf16(a2A[ks], w, cA, 0, 0, 0);
                cB = __builtin_amdgcn_mfma_f32_16x16x32_bf16(a2B[ks], w, cB, 0, 0, 0);
            }
            float mxA = fmaxf(fmaxf(cA[0], cA[1]), fmaxf(cA[2], cA[3]));
            float mnA = fminf(fminf(cA[0], cA[1]), fminf(cA[2], cA[3]));
            float mxB = fmaxf(fmaxf(cB[0], cB[1]), fmaxf(cB[2], cB[3]));
            float mnB = fminf(fminf(cB[0], cB[1]), fminf(cB[2], cB[3]));
            mxA = fmaxf(mxA, __shfl_xor(mxA, 16, 64));
            mxA = fmaxf(mxA, __shfl_xor(mxA, 32, 64));
            mnA = fminf(mnA, __shfl_xor(mnA, 16, 64));
            mnA = fminf(mnA, __shfl_xor(mnA, 32, 64));
            mxB = fmaxf(mxB, __shfl_xor(mxB, 16, 64));
            mxB = fmaxf(mxB, __shfl_xor(mxB, 32, 64));
            mnB = fminf(mnB, __shfl_xor(mnB, 16, 64));
            mnB = fminf(mnB, __shfl_xor(mnB, 32, 64));
            vA[nt] = fmaxf(gelu(mxA + b2v[nt]), gelu(mnA + b2v[nt]));
            vB[nt] = fmaxf(gelu(mxB + b2v[nt]), gelu(mnB + b2v[nt]));
        }

        // layernorm + store
        #pragma unroll
        for (int u = 0; u < 2; ++u) {
            const float* v = u ? vB : vA;
            float s = 0.f, s2 = 0.f;
            #pragma unroll
            for (int nt = 0; nt < 8; ++nt) { s += v[nt]; s2 += v[nt] * v[nt]; }
            #pragma unroll
            for (int off = 1; off <= 8; off <<= 1) {
                s  += __shfl_xor(s,  off, 64);
                s2 += __shfl_xor(s2, off, 64);
            }
            const float mu  = s * (1.0f / 128.0f);
            const float var = s2 * (1.0f / 128.0f) - mu * mu;
            const float inv = rsqrtf(var + 1e-5f);
            float* orow = out + (size_t)(node0 + pr * 2 + u) * 128;
            orow[(quad * 2) * 16 + lm]     = (v[quad * 2]     - mu) * inv * gv0 + be0;
            orow[(quad * 2 + 1) * 16 + lm] = (v[quad * 2 + 1] - mu) * inv * gv1 + be1;
        }
    }
}

extern "C" void kernel_launch(void* const* d_in, const int* in_sizes, int n_in,
                              void* d_out, int out_size, void* d_ws, size_t ws_size,
                              hipStream_t stream) {
    const float* h     = (const float*)d_in[0];
    const float* pos   = (const float*)d_in[1];
    const int*   idx   = (const int*)  d_in[2];
    const float* W1    = (const float*)d_in[3];
    const float* b1    = (const float*)d_in[4];
    const float* W2    = (const float*)d_in[5];
    const float* b2    = (const float*)d_in[6];
    const float* gamma = (const float*)d_in[7];
    const float* beta  = (const float*)d_in[8];
    float* out = (float*)d_out;

    hipFuncSetAttribute((const void*)edgeconv_fused,
                        hipFuncAttributeMaxDynamicSharedMemorySize, LDS_BYTES);
    edgeconv_fused<<<256, 1024, LDS_BYTES, stream>>>(
        h, pos, idx, W1, W2, b1, b2, gamma, beta, out);
}